// Round 20
// baseline (8900.480 us; speedup 1.0000x reference)
//
#include <hip/hip_runtime.h>
#include <cstdint>
#include <cstddef>

#define TDIM 512
#define BDIM 64
#define IDIM 512
#define HDIM 1024
#define SPIN_CAP 20000u
#define NREP 4  // fallback path only
#define CAN64 0x7FC07FC07FC07FC0ULL  // bf16 NaN x4: impossible as finite data

typedef __attribute__((ext_vector_type(8))) short s16x8;
typedef __attribute__((ext_vector_type(4))) float f32x4;

__device__ __forceinline__ unsigned short f2bf(float f) {
  unsigned u = __builtin_bit_cast(unsigned, f);
  u += 0x7FFFu + ((u >> 16) & 1u);
  return (unsigned short)(u >> 16);
}
__device__ __forceinline__ float sigmf(float x) { return 1.0f / (1.0f + __expf(-x)); }
__device__ __forceinline__ unsigned pk2(float a, float b) {
  return (unsigned)f2bf(a) | ((unsigned)f2bf(b) << 16);
}
#define MFMA16(a, b, c) __builtin_amdgcn_mfma_f32_16x16x32_bf16((a), (b), (c), 0, 0, 0)

__device__ __forceinline__ s16x8 ld16_llc(const unsigned long long* p) {
  s16x8 v;
  asm volatile("global_load_dwordx4 %0, %1, off sc0 sc1" : "=v"(v) : "v"(p));
  return v;
}
__device__ __forceinline__ void sysst64(unsigned long long* p, unsigned long long v) {
  __hip_atomic_store(p, v, __ATOMIC_RELAXED, __HIP_MEMORY_SCOPE_SYSTEM);
}

// ---------------- x convert ----------------
__global__ __launch_bounds__(256) void k_xcvt(const float* __restrict__ x,
                                              unsigned short* __restrict__ xbf) {
  int idx = blockIdx.x * 256 + threadIdx.x;
  int i8 = idx * 8;
  int i = i8 & (IDIM - 1);
  int tb = i8 >> 9;
  int t = tb >> 6, b = tb & 63;
  const float* src = x + ((size_t)(b * TDIM + t)) * IDIM + i;
  float4 a = *(const float4*)src;
  float4 c = *(const float4*)(src + 4);
  uint4 v;
  v.x = pk2(a.x, a.y); v.y = pk2(a.z, a.w);
  v.z = pk2(c.x, c.y); v.w = pk2(c.z, c.w);
  *(uint4*)(xbf + i8) = v;
}

// ---------------- canary prefill ----------------
__global__ __launch_bounds__(256) void k_fill(unsigned long long* __restrict__ p, size_t n) {
  size_t stride = (size_t)gridDim.x * 256 * 2;
  for (size_t i = ((size_t)blockIdx.x * 256 + threadIdx.x) * 2; i < n; i += stride) {
    p[i] = CAN64;
    p[i + 1] = CAN64;
  }
}

// ================= BIG PATH: flagless NaN-canary pipeline =================
// grid = 256 WGs x 128 thr. dir = wg>>7, half = (wg>>6)&1, cg = wg&63.
// hist per chain: TDIM x 8192 u64, prefilled with CAN64. Producers store
// (relaxed system scope) with NO ack/barrier/flag; consumers validate each 16B
// fragment != canary, retrying stale ones via sc0/sc1 loads. Write-once =>
// no ABA, no WAR, unbounded producer lead allowed.
__global__ __launch_bounds__(128, 1) void k_gru_big(
    const unsigned short* __restrict__ xbf,
    const float* __restrict__ wihf32f, const float* __restrict__ wihf32b,
    const float* __restrict__ whhf32f, const float* __restrict__ whhf32b,
    const float* __restrict__ bih_f, const float* __restrict__ bhh_f,
    const float* __restrict__ bih_b, const float* __restrict__ bhh_b,
    const float* __restrict__ attw,
    unsigned long long* __restrict__ ghist, float* __restrict__ attp) {
  __shared__ uint4 lds4[147456 / 16];
  char* lds = (char*)lds4;
  const int wg = blockIdx.x;
  const int dir = wg >> 7, half = (wg >> 6) & 1, cg = wg & 63;
  const int tid = threadIdx.x, w = tid >> 6, l = tid & 63;
  const int r = l & 15, q = l >> 4;
  const int col = cg * 16 + r;
  const float* wih = dir ? wihf32b : wihf32f;
  const float* whh = dir ? whhf32b : whhf32f;
  const float* bih = dir ? bih_b : bih_f;
  const float* bhh = dir ? bhh_b : bhh_f;
  unsigned long long* hist = ghist + (size_t)(dir * 2 + half) * ((size_t)TDIM * 8192);

  for (int it = tid; it < 48 * 128; it += 128) {
    int row = it >> 7, ch = it & 127;
    int g = row >> 4, rr = row & 15;
    const float* src = whh + ((size_t)(g * HDIM + cg * 16 + rr)) * HDIM + ch * 8;
    float4 f0 = *(const float4*)src;
    float4 f1 = *(const float4*)(src + 4);
    uint4 v;
    v.x = pk2(f0.x, f0.y); v.y = pk2(f0.z, f0.w);
    v.z = pk2(f1.x, f1.y); v.w = pk2(f1.z, f1.w);
    *(uint4*)(lds + row * 2048 + ((ch * 16) ^ ((row & 7) << 4))) = v;
  }
  for (int it = tid; it < 48 * 64; it += 128) {
    int row = it >> 6, ch = it & 63;
    int g = row >> 4, rr = row & 15;
    const float* src = wih + ((size_t)(g * HDIM + cg * 16 + rr)) * IDIM + ch * 8;
    float4 f0 = *(const float4*)src;
    float4 f1 = *(const float4*)(src + 4);
    uint4 v;
    v.x = pk2(f0.x, f0.y); v.y = pk2(f0.z, f0.w);
    v.z = pk2(f1.x, f1.y); v.w = pk2(f1.z, f1.w);
    *(uint4*)(lds + 98304 + row * 1024 + ((ch * 16) ^ ((row & 7) << 4))) = v;
  }
  __syncthreads();

  const float br = bih[col] + bhh[col];
  const float bz = bih[col + HDIM] + bhh[col + HDIM];
  const float bnx = bih[col + 2 * HDIM];
  const float bnh = bhh[col + 2 * HDIM];
  const float wfc = attw[dir * HDIM + col];
  const int swz = (r & 7) << 4;
  const int bb = half * 32 + w * 16;
  float h[4] = {0.f, 0.f, 0.f, 0.f};

  for (int t = 0; t < TDIM; ++t) {
    const int tt = dir ? (TDIM - 1 - t) : t;
    f32x4 aR = {}, aZ = {}, aNx = {}, aNh = {};
    {
      const unsigned short* px = xbf + ((size_t)(tt * BDIM + bb + r)) * IDIM + q * 8;
#pragma unroll 4
      for (int kt = 0; kt < 16; ++kt) {
        s16x8 a = *(const s16x8*)(px + kt * 32);
        int kb = q * 16 + kt * 64;
        s16x8 b0 = *(const s16x8*)(lds + 98304 + r * 1024 + (kb ^ swz));
        s16x8 b1 = *(const s16x8*)(lds + 98304 + (16 + r) * 1024 + (kb ^ swz));
        s16x8 b2 = *(const s16x8*)(lds + 98304 + (32 + r) * 1024 + (kb ^ swz));
        aR = MFMA16(a, b0, aR);
        aZ = MFMA16(a, b1, aZ);
        aNx = MFMA16(a, b2, aNx);
      }
    }
    if (t > 0) {
      const unsigned long long* ph = hist + (size_t)(t - 1) * 8192 + (w * 16 + r) * 256 + q * 2;
      union { s16x8 v; unsigned long long u[2]; } ha[32];
#pragma unroll
      for (int i = 0; i < 32; ++i) ha[i].v = ld16_llc(ph + ((i + cg) & 31) * 8);
      asm volatile("s_waitcnt vmcnt(0)" ::: "memory");
      __builtin_amdgcn_sched_barrier(0);
#pragma unroll
      for (int i = 0; i < 32; ++i) {
        const int kro = (i + cg) & 31;
        for (unsigned spin = 0;; ++spin) {
          bool bad = (ha[i].u[0] == CAN64) || (ha[i].u[1] == CAN64);
          if (!__any((int)bad)) break;
          if (spin > SPIN_CAP) break;  // watchdog
          if (bad) {
            ha[i].v = ld16_llc(ph + kro * 8);
            asm volatile("s_waitcnt vmcnt(0)" ::: "memory");
          }
        }
        int kb = q * 16 + kro * 64;
        s16x8 b0 = *(const s16x8*)(lds + r * 2048 + (kb ^ swz));
        s16x8 b1 = *(const s16x8*)(lds + (16 + r) * 2048 + (kb ^ swz));
        s16x8 b2 = *(const s16x8*)(lds + (32 + r) * 2048 + (kb ^ swz));
        aR = MFMA16(ha[i].v, b0, aR);
        aZ = MFMA16(ha[i].v, b1, aZ);
        aNh = MFMA16(ha[i].v, b2, aNh);
      }
    }
    unsigned long long* hn = hist + (size_t)t * 8192;
    float sa[4];
#pragma unroll
    for (int j = 0; j < 4; ++j) {
      const int lb = w * 16 + q * 4 + j;
      float rg = sigmf(aR[j] + br);
      float zg = sigmf(aZ[j] + bz);
      float ng = tanhf(aNx[j] + bnx + rg * (aNh[j] + bnh));
      float hv = (1.0f - zg) * ng + zg * h[j];
      h[j] = hv;
      sa[j] = hv * wfc;
      unsigned p2 = pk2(hv, __shfl_xor(hv, 1, 64));
      unsigned p2o = __shfl_xor(p2, 2, 64);
      if ((r & 3) == 0) {
        unsigned long long v64 = (unsigned long long)p2 | ((unsigned long long)p2o << 32);
        sysst64(&hn[(size_t)lb * 256 + cg * 4 + (r >> 2)], v64);
      }
    }
    // no ack, no barrier, no flag: consumers validate via canary
    {
      float* ap = attp + (size_t)(dir * 64 + cg) * (TDIM * BDIM) + tt * BDIM;
#pragma unroll
      for (int j = 0; j < 4; ++j) {
        const int b = half * 32 + w * 16 + q * 4 + j;
        float s = sa[j];
        s += __shfl_xor(s, 1, 64);
        s += __shfl_xor(s, 2, 64);
        s += __shfl_xor(s, 4, 64);
        s += __shfl_xor(s, 8, 64);
        if (r == 0) ap[b] = s;
      }
    }
  }
}

__global__ __launch_bounds__(128, 1) void k_scan3_big(
    const unsigned short* __restrict__ xbf,
    const float* __restrict__ i2hf32, const float* __restrict__ h2hf32,
    const float* __restrict__ i2hb, const float* __restrict__ h2hb,
    const float* __restrict__ att,
    unsigned long long* __restrict__ shist, float* __restrict__ hlast) {
  __shared__ uint4 lds4[49152 / 16];
  char* lds = (char*)lds4;
  const int wg = blockIdx.x;
  const int half = wg >> 6, cg = wg & 63;
  const int tid = threadIdx.x, w = tid >> 6, l = tid & 63;
  const int r = l & 15, q = l >> 4;
  const int col = cg * 16 + r;
  unsigned long long* hist = shist + (size_t)half * ((size_t)TDIM * 8192);
  for (int it = tid; it < 16 * 128; it += 128) {
    int row = it >> 7, ch = it & 127;
    const float* src = h2hf32 + ((size_t)(cg * 16 + row)) * HDIM + ch * 8;
    float4 f0 = *(const float4*)src;
    float4 f1 = *(const float4*)(src + 4);
    uint4 v;
    v.x = pk2(f0.x, f0.y); v.y = pk2(f0.z, f0.w);
    v.z = pk2(f1.x, f1.y); v.w = pk2(f1.z, f1.w);
    *(uint4*)(lds + row * 2048 + ((ch * 16) ^ ((row & 7) << 4))) = v;
  }
  for (int it = tid; it < 16 * 64; it += 128) {
    int row = it >> 6, ch = it & 63;
    const float* src = i2hf32 + ((size_t)(cg * 16 + row)) * IDIM + ch * 8;
    float4 f0 = *(const float4*)src;
    float4 f1 = *(const float4*)(src + 4);
    uint4 v;
    v.x = pk2(f0.x, f0.y); v.y = pk2(f0.z, f0.w);
    v.z = pk2(f1.x, f1.y); v.w = pk2(f1.z, f1.w);
    *(uint4*)(lds + 32768 + row * 1024 + ((ch * 16) ^ ((row & 7) << 4))) = v;
  }
  __syncthreads();
  const float bc = i2hb[col] + h2hb[col];
  const int swz = (r & 7) << 4;
  const int bb = half * 32 + w * 16;
  float h[4] = {0.f, 0.f, 0.f, 0.f};
  for (int t = 0; t < TDIM; ++t) {
    f32x4 ac = {};
    {
      const unsigned short* px = xbf + ((size_t)(t * BDIM + bb + r)) * IDIM + q * 8;
#pragma unroll 4
      for (int kt = 0; kt < 16; ++kt) {
        s16x8 a = *(const s16x8*)(px + kt * 32);
        int kb = q * 16 + kt * 64;
        s16x8 b = *(const s16x8*)(lds + 32768 + r * 1024 + (kb ^ swz));
        ac = MFMA16(a, b, ac);
      }
    }
    if (t > 0) {
      const unsigned long long* ph = hist + (size_t)(t - 1) * 8192 + (w * 16 + r) * 256 + q * 2;
      union { s16x8 v; unsigned long long u[2]; } ha[32];
#pragma unroll
      for (int i = 0; i < 32; ++i) ha[i].v = ld16_llc(ph + ((i + cg) & 31) * 8);
      asm volatile("s_waitcnt vmcnt(0)" ::: "memory");
      __builtin_amdgcn_sched_barrier(0);
#pragma unroll
      for (int i = 0; i < 32; ++i) {
        const int kro = (i + cg) & 31;
        for (unsigned spin = 0;; ++spin) {
          bool bad = (ha[i].u[0] == CAN64) || (ha[i].u[1] == CAN64);
          if (!__any((int)bad)) break;
          if (spin > SPIN_CAP) break;  // watchdog
          if (bad) {
            ha[i].v = ld16_llc(ph + kro * 8);
            asm volatile("s_waitcnt vmcnt(0)" ::: "memory");
          }
        }
        int kb = q * 16 + kro * 64;
        s16x8 b = *(const s16x8*)(lds + r * 2048 + (kb ^ swz));
        ac = MFMA16(ha[i].v, b, ac);
      }
    }
    unsigned long long* hn = hist + (size_t)t * 8192;
    const float* ab = att + (size_t)t * BDIM;
#pragma unroll
    for (int j = 0; j < 4; ++j) {
      const int lb = w * 16 + q * 4 + j;
      float tr = fmaxf(ac[j] + bc, 0.0f);
      float a = ab[half * 32 + lb];
      float hv = a * tr + (1.0f - a) * h[j];
      h[j] = hv;
      unsigned p2 = pk2(hv, __shfl_xor(hv, 1, 64));
      unsigned p2o = __shfl_xor(p2, 2, 64);
      if ((r & 3) == 0) {
        unsigned long long v64 = (unsigned long long)p2 | ((unsigned long long)p2o << 32);
        sysst64(&hn[(size_t)lb * 256 + cg * 4 + (r >> 2)], v64);
      }
    }
  }
#pragma unroll
  for (int j = 0; j < 4; ++j) {
    const int b = half * 32 + w * 16 + q * 4 + j;
    hlast[b * HDIM + col] = h[j];
  }
}

// ================= FALLBACK PATH (round-18, passing at 8.0 ms) =================
__global__ __launch_bounds__(128, 1) void k_gru_fused(
    const unsigned short* __restrict__ xbf,
    const float* __restrict__ wihf32f, const float* __restrict__ wihf32b,
    const float* __restrict__ whhf32f, const float* __restrict__ whhf32b,
    const float* __restrict__ bih_f, const float* __restrict__ bhh_f,
    const float* __restrict__ bih_b, const float* __restrict__ bhh_b,
    const float* __restrict__ attw,
    unsigned long long* __restrict__ hbufu, float* __restrict__ attp,
    unsigned int* __restrict__ flags) {
  __shared__ uint4 lds4[147456 / 16];
  char* lds = (char*)lds4;
  const int wg = blockIdx.x;
  const int dir = wg >> 7, half = (wg >> 6) & 1, cg = wg & 63;
  const int tid = threadIdx.x, w = tid >> 6, l = tid & 63;
  const int r = l & 15, q = l >> 4;
  const int col = cg * 16 + r;
  const float* wih = dir ? wihf32b : wihf32f;
  const float* whh = dir ? whhf32b : whhf32f;
  const float* bih = dir ? bih_b : bih_f;
  const float* bhh = dir ? bhh_b : bhh_f;
  unsigned int* myflags = flags + (dir * 2 + half) * 1024;
  unsigned long long* hb0 = hbufu + (size_t)(dir * 2 + half) * (NREP * 2 * 8192);

  for (int it = tid; it < 48 * 128; it += 128) {
    int row = it >> 7, ch = it & 127;
    int g = row >> 4, rr = row & 15;
    const float* src = whh + ((size_t)(g * HDIM + cg * 16 + rr)) * HDIM + ch * 8;
    float4 f0 = *(const float4*)src;
    float4 f1 = *(const float4*)(src + 4);
    uint4 v;
    v.x = pk2(f0.x, f0.y); v.y = pk2(f0.z, f0.w);
    v.z = pk2(f1.x, f1.y); v.w = pk2(f1.z, f1.w);
    *(uint4*)(lds + row * 2048 + ((ch * 16) ^ ((row & 7) << 4))) = v;
  }
  for (int it = tid; it < 48 * 64; it += 128) {
    int row = it >> 6, ch = it & 63;
    int g = row >> 4, rr = row & 15;
    const float* src = wih + ((size_t)(g * HDIM + cg * 16 + rr)) * IDIM + ch * 8;
    float4 f0 = *(const float4*)src;
    float4 f1 = *(const float4*)(src + 4);
    uint4 v;
    v.x = pk2(f0.x, f0.y); v.y = pk2(f0.z, f0.w);
    v.z = pk2(f1.x, f1.y); v.w = pk2(f1.z, f1.w);
    *(uint4*)(lds + 98304 + row * 1024 + ((ch * 16) ^ ((row & 7) << 4))) = v;
  }
  __syncthreads();

  const float br = bih[col] + bhh[col];
  const float bz = bih[col + HDIM] + bhh[col + HDIM];
  const float bnx = bih[col + 2 * HDIM];
  const float bnh = bhh[col + 2 * HDIM];
  const float wfc = attw[dir * HDIM + col];
  const int swz = (r & 7) << 4;
  const int bb = half * 32 + w * 16;
  float h[4] = {0.f, 0.f, 0.f, 0.f};

  for (int t = 0; t < TDIM; ++t) {
    const int tt = dir ? (TDIM - 1 - t) : t;
    f32x4 aR = {}, aZ = {}, aNx = {}, aNh = {};
    {
      const unsigned short* px = xbf + ((size_t)(tt * BDIM + bb + r)) * IDIM + q * 8;
#pragma unroll 4
      for (int kt = 0; kt < 16; ++kt) {
        s16x8 a = *(const s16x8*)(px + kt * 32);
        int kb = q * 16 + kt * 64;
        s16x8 b0 = *(const s16x8*)(lds + 98304 + r * 1024 + (kb ^ swz));
        s16x8 b1 = *(const s16x8*)(lds + 98304 + (16 + r) * 1024 + (kb ^ swz));
        s16x8 b2 = *(const s16x8*)(lds + 98304 + (32 + r) * 1024 + (kb ^ swz));
        aR = MFMA16(a, b0, aR);
        aZ = MFMA16(a, b1, aZ);
        aNx = MFMA16(a, b2, aNx);
      }
    }
    if (t > 0) {
      for (unsigned spin = 0;; ++spin) {
        unsigned v = __hip_atomic_load(&myflags[l * 16], __ATOMIC_RELAXED, __HIP_MEMORY_SCOPE_SYSTEM);
        if (__all((int)(v >= (unsigned)t))) break;
        if (spin > SPIN_CAP) break;
      }
      __builtin_amdgcn_sched_barrier(0);
    }
    {
      const unsigned long long* ph = hb0 + (size_t)(cg & (NREP - 1)) * 16384 +
                                     (size_t)(t & 1) * 8192 + (w * 16 + r) * 256 + q * 2;
      s16x8 ha[32];
#pragma unroll
      for (int i = 0; i < 32; ++i) {
        int kro = (i + cg) & 31;
        ha[i] = ld16_llc(ph + kro * 8);
      }
      asm volatile("s_waitcnt vmcnt(0)" ::: "memory");
      __builtin_amdgcn_sched_barrier(0);
#pragma unroll
      for (int i = 0; i < 32; ++i) {
        int kro = (i + cg) & 31;
        int kb = q * 16 + kro * 64;
        s16x8 b0 = *(const s16x8*)(lds + r * 2048 + (kb ^ swz));
        s16x8 b1 = *(const s16x8*)(lds + (16 + r) * 2048 + (kb ^ swz));
        s16x8 b2 = *(const s16x8*)(lds + (32 + r) * 2048 + (kb ^ swz));
        aR = MFMA16(ha[i], b0, aR);
        aZ = MFMA16(ha[i], b1, aZ);
        aNh = MFMA16(ha[i], b2, aNh);
      }
    }
    unsigned long long* hn = hb0 + (size_t)((t + 1) & 1) * 8192;
    float sa[4];
#pragma unroll
    for (int j = 0; j < 4; ++j) {
      const int lb = w * 16 + q * 4 + j;
      float rg = sigmf(aR[j] + br);
      float zg = sigmf(aZ[j] + bz);
      float ng = tanhf(aNx[j] + bnx + rg * (aNh[j] + bnh));
      float hv = (1.0f - zg) * ng + zg * h[j];
      h[j] = hv;
      sa[j] = hv * wfc;
      unsigned p2 = pk2(hv, __shfl_xor(hv, 1, 64));
      unsigned p2o = __shfl_xor(p2, 2, 64);
      if ((r & 3) == 0) {
        unsigned long long v64 = (unsigned long long)p2 | ((unsigned long long)p2o << 32);
        size_t off = (size_t)lb * 256 + cg * 4 + (r >> 2);
#pragma unroll
        for (int rep = 0; rep < NREP; ++rep)
          sysst64(&hn[(size_t)rep * 16384 + off], v64);
      }
    }
    asm volatile("s_waitcnt vmcnt(0)" ::: "memory");
    __syncthreads();
    if (tid == 0)
      __hip_atomic_store(&myflags[cg * 16], (unsigned)(t + 1),
                         __ATOMIC_RELAXED, __HIP_MEMORY_SCOPE_SYSTEM);
    {
      float* ap = attp + (size_t)(dir * 64 + cg) * (TDIM * BDIM) + tt * BDIM;
#pragma unroll
      for (int j = 0; j < 4; ++j) {
        const int b = half * 32 + w * 16 + q * 4 + j;
        float s = sa[j];
        s += __shfl_xor(s, 1, 64);
        s += __shfl_xor(s, 2, 64);
        s += __shfl_xor(s, 4, 64);
        s += __shfl_xor(s, 8, 64);
        if (r == 0) ap[b] = s;
      }
    }
  }
}

__global__ __launch_bounds__(128, 1) void k_scan3(
    const unsigned short* __restrict__ xbf,
    const float* __restrict__ i2hf32, const float* __restrict__ h2hf32,
    const float* __restrict__ i2hb, const float* __restrict__ h2hb,
    const float* __restrict__ att,
    unsigned long long* __restrict__ h3u, float* __restrict__ hlast,
    unsigned int* __restrict__ flags3) {
  __shared__ uint4 lds4[49152 / 16];
  char* lds = (char*)lds4;
  const int wg = blockIdx.x;
  const int half = wg >> 6, cg = wg & 63;
  const int tid = threadIdx.x, w = tid >> 6, l = tid & 63;
  const int r = l & 15, q = l >> 4;
  const int col = cg * 16 + r;
  unsigned int* myflags = flags3 + half * 1024;
  unsigned long long* hb0 = h3u + (size_t)half * (NREP * 2 * 8192);
  for (int it = tid; it < 16 * 128; it += 128) {
    int row = it >> 7, ch = it & 127;
    const float* src = h2hf32 + ((size_t)(cg * 16 + row)) * HDIM + ch * 8;
    float4 f0 = *(const float4*)src;
    float4 f1 = *(const float4*)(src + 4);
    uint4 v;
    v.x = pk2(f0.x, f0.y); v.y = pk2(f0.z, f0.w);
    v.z = pk2(f1.x, f1.y); v.w = pk2(f1.z, f1.w);
    *(uint4*)(lds + row * 2048 + ((ch * 16) ^ ((row & 7) << 4))) = v;
  }
  for (int it = tid; it < 16 * 64; it += 128) {
    int row = it >> 6, ch = it & 63;
    const float* src = i2hf32 + ((size_t)(cg * 16 + row)) * IDIM + ch * 8;
    float4 f0 = *(const float4*)src;
    float4 f1 = *(const float4*)(src + 4);
    uint4 v;
    v.x = pk2(f0.x, f0.y); v.y = pk2(f0.z, f0.w);
    v.z = pk2(f1.x, f1.y); v.w = pk2(f1.z, f1.w);
    *(uint4*)(lds + 32768 + row * 1024 + ((ch * 16) ^ ((row & 7) << 4))) = v;
  }
  __syncthreads();
  const float bc = i2hb[col] + h2hb[col];
  const int swz = (r & 7) << 4;
  const int bb = half * 32 + w * 16;
  float h[4] = {0.f, 0.f, 0.f, 0.f};
  for (int t = 0; t < TDIM; ++t) {
    f32x4 ac = {};
    {
      const unsigned short* px = xbf + ((size_t)(t * BDIM + bb + r)) * IDIM + q * 8;
#pragma unroll 4
      for (int kt = 0; kt < 16; ++kt) {
        s16x8 a = *(const s16x8*)(px + kt * 32);
        int kb = q * 16 + kt * 64;
        s16x8 b = *(const s16x8*)(lds + 32768 + r * 1024 + (kb ^ swz));
        ac = MFMA16(a, b, ac);
      }
    }
    if (t > 0) {
      for (unsigned spin = 0;; ++spin) {
        unsigned v = __hip_atomic_load(&myflags[l * 16], __ATOMIC_RELAXED, __HIP_MEMORY_SCOPE_SYSTEM);
        if (__all((int)(v >= (unsigned)t))) break;
        if (spin > SPIN_CAP) break;
      }
      __builtin_amdgcn_sched_barrier(0);
    }
    {
      const unsigned long long* ph = hb0 + (size_t)(cg & (NREP - 1)) * 16384 +
                                     (size_t)(t & 1) * 8192 + (w * 16 + r) * 256 + q * 2;
      s16x8 ha[32];
#pragma unroll
      for (int i = 0; i < 32; ++i) {
        int kro = (i + cg) & 31;
        ha[i] = ld16_llc(ph + kro * 8);
      }
      asm volatile("s_waitcnt vmcnt(0)" ::: "memory");
      __builtin_amdgcn_sched_barrier(0);
#pragma unroll
      for (int i = 0; i < 32; ++i) {
        int kro = (i + cg) & 31;
        int kb = q * 16 + kro * 64;
        s16x8 b = *(const s16x8*)(lds + r * 2048 + (kb ^ swz));
        ac = MFMA16(ha[i], b, ac);
      }
    }
    unsigned long long* hn = hb0 + (size_t)((t + 1) & 1) * 8192;
    const float* ab = att + (size_t)t * BDIM;
#pragma unroll
    for (int j = 0; j < 4; ++j) {
      const int lb = w * 16 + q * 4 + j;
      float tr = fmaxf(ac[j] + bc, 0.0f);
      float a = ab[half * 32 + lb];
      float hv = a * tr + (1.0f - a) * h[j];
      h[j] = hv;
      unsigned p2 = pk2(hv, __shfl_xor(hv, 1, 64));
      unsigned p2o = __shfl_xor(p2, 2, 64);
      if ((r & 3) == 0) {
        unsigned long long v64 = (unsigned long long)p2 | ((unsigned long long)p2o << 32);
        size_t off = (size_t)lb * 256 + cg * 4 + (r >> 2);
#pragma unroll
        for (int rep = 0; rep < NREP; ++rep)
          sysst64(&hn[(size_t)rep * 16384 + off], v64);
      }
    }
    asm volatile("s_waitcnt vmcnt(0)" ::: "memory");
    __syncthreads();
    if (tid == 0)
      __hip_atomic_store(&myflags[cg * 16], (unsigned)(t + 1),
                         __ATOMIC_RELAXED, __HIP_MEMORY_SCOPE_SYSTEM);
  }
#pragma unroll
  for (int j = 0; j < 4; ++j) {
    const int b = half * 32 + w * 16 + q * 4 + j;
    hlast[b * HDIM + col] = h[j];
  }
}

// ---------------- shared epilogue kernels ----------------
__global__ __launch_bounds__(256) void k_attf(const float* __restrict__ attp,
                                              const float* __restrict__ fcb,
                                              float* __restrict__ att,
                                              float* __restrict__ att_out) {
  int idx = blockIdx.x * 256 + threadIdx.x;
  float s = fcb[0];
  for (int g = 0; g < 128; ++g) s += attp[(size_t)g * (TDIM * BDIM) + idx];
  float a = sigmf(3.0f * s);
  att[idx] = a;
  int t = idx >> 6, b = idx & 63;
  att_out[(size_t)b * TDIM + t] = a;
}

__global__ __launch_bounds__(256) void k_fc(const float* __restrict__ A,
                                            const float* __restrict__ W,
                                            const float* __restrict__ bias,
                                            float* __restrict__ dst) {
  const int idx = blockIdx.x * 256 + threadIdx.x;
  const int rr = idx >> 10, c = idx & 1023;
  const float4* a = (const float4*)(A + (size_t)rr * HDIM);
  const float4* w = (const float4*)(W + (size_t)c * HDIM);
  float s = bias[c];
  for (int k = 0; k < HDIM / 4; ++k) {
    float4 xx = a[k], y = w[k];
    s += xx.x * y.x + xx.y * y.y + xx.z * y.z + xx.w * y.w;
  }
  dst[idx] = s;
}

__global__ __launch_bounds__(256) void k_diag(float* out, int n, float val) {
  int i = blockIdx.x * 256 + threadIdx.x;
  if (i < n) out[i] = val;
}

extern "C" void kernel_launch(void* const* d_in, const int* in_sizes, int n_in,
                              void* d_out, int out_size, void* d_ws, size_t ws_size,
                              hipStream_t stream) {
  float* outF = (float*)d_out;
  int diag_blocks = (out_size + 255) / 256;

  static const int exp_sizes[19] = {16777216, 1572864, 3145728, 3072, 3072,
                                    1572864, 3145728, 3072, 3072, 2048, 1,
                                    524288, 1024, 1048576, 1024, 1048576, 1024,
                                    1048576, 1024};
  if (n_in != 19) {
    k_diag<<<diag_blocks, 256, 0, stream>>>(outF, out_size, 3999.0f);
    return;
  }
  for (int i = 0; i < 19; ++i) {
    if (in_sizes[i] != exp_sizes[i]) {
      k_diag<<<diag_blocks, 256, 0, stream>>>(outF, out_size, (float)(4000 + i * 16));
      return;
    }
  }

  const float* x     = (const float*)d_in[0];
  const float* wih_f = (const float*)d_in[1];
  const float* whh_f = (const float*)d_in[2];
  const float* bih_f = (const float*)d_in[3];
  const float* bhh_f = (const float*)d_in[4];
  const float* wih_b = (const float*)d_in[5];
  const float* whh_b = (const float*)d_in[6];
  const float* bih_b = (const float*)d_in[7];
  const float* bhh_b = (const float*)d_in[8];
  const float* fc_w  = (const float*)d_in[9];
  const float* fc_b  = (const float*)d_in[10];
  const float* i2h_w = (const float*)d_in[11];
  const float* i2h_b = (const float*)d_in[12];
  const float* h2h_w = (const float*)d_in[13];
  const float* h2h_b = (const float*)d_in[14];
  const float* fc0_w = (const float*)d_in[15];
  const float* fc0_b = (const float*)d_in[16];
  const float* fc1_w = (const float*)d_in[17];
  const float* fc1_b = (const float*)d_in[18];

  const size_t OFF_XBF  = 0;           // 33,554,432
  const size_t OFF_ATTP = 33554432;    // 16,777,216
  const size_t OFF_ATT  = 50331648;    //    131,072

  // BIG layout
  const size_t OFF_GHIST = 50462720;                 // 134,217,728
  const size_t OFF_SHIST = OFF_GHIST + 134217728;    //  67,108,864
  const size_t OFF_HLAST_B = OFF_SHIST + 67108864;   //     262,144
  const size_t OFF_OUT1_B  = OFF_HLAST_B + 262144;   //     262,144
  const size_t OFF_FLAGS_B = OFF_OUT1_B + 262144;    //      24,576
  const size_t TOTAL_BIG   = OFF_FLAGS_B + 24576;

  // FALLBACK layout (round-18)
  const size_t OFF_HBUF  = 50462720;
  const size_t OFF_H3BUF = 52559872;
  const size_t OFF_HLAST = 53608448;
  const size_t OFF_OUT1  = 53870592;
  const size_t OFF_FLAGS = 54132736;
  const size_t TOTAL_SMALL = 54157312;

  if (ws_size < TOTAL_SMALL) {
    k_diag<<<diag_blocks, 256, 0, stream>>>(outF, out_size, (float)(ws_size >> 20));
    return;
  }

  char* ws = (char*)d_ws;
  unsigned short* xbf = (unsigned short*)(ws + OFF_XBF);
  float* attp         = (float*)(ws + OFF_ATTP);
  float* att          = (float*)(ws + OFF_ATT);

  k_xcvt<<<8192, 256, 0, stream>>>(x, xbf);

  if (ws_size >= TOTAL_BIG) {
    // ---------- BIG PATH: flagless canary pipeline ----------
    unsigned long long* ghist = (unsigned long long*)(ws + OFF_GHIST);
    unsigned long long* shist = (unsigned long long*)(ws + OFF_SHIST);
    float* hlast              = (float*)(ws + OFF_HLAST_B);
    float* out1               = (float*)(ws + OFF_OUT1_B);

    // prefill both histories (contiguous) with canary
    k_fill<<<2048, 256, 0, stream>>>(ghist, (size_t)(134217728 + 67108864) / 8);

    k_gru_big<<<256, 128, 0, stream>>>(xbf, wih_f, wih_b, whh_f, whh_b,
                                       bih_f, bhh_f, bih_b, bhh_b, fc_w,
                                       ghist, attp);
    k_attf<<<128, 256, 0, stream>>>(attp, fc_b, att, outF + 65536);
    k_scan3_big<<<128, 128, 0, stream>>>(xbf, i2h_w, h2h_w, i2h_b, h2h_b, att,
                                         shist, hlast);
    k_fc<<<256, 256, 0, stream>>>(hlast, fc0_w, fc0_b, out1);
    k_fc<<<256, 256, 0, stream>>>(out1, fc1_w, fc1_b, outF);
  } else {
    // ---------- FALLBACK (round-18) ----------
    unsigned long long* hbufu = (unsigned long long*)(ws + OFF_HBUF);
    unsigned long long* h3u   = (unsigned long long*)(ws + OFF_H3BUF);
    float* hlast              = (float*)(ws + OFF_HLAST);
    float* out1               = (float*)(ws + OFF_OUT1);
    unsigned int* flags       = (unsigned int*)(ws + OFF_FLAGS);

    hipMemsetAsync(flags, 0, 24576, stream);
    hipMemsetAsync(hbufu, 0, 2097152, stream);
    hipMemsetAsync(h3u, 0, 1048576, stream);

    k_gru_fused<<<256, 128, 0, stream>>>(xbf, wih_f, wih_b, whh_f, whh_b,
                                         bih_f, bhh_f, bih_b, bhh_b, fc_w,
                                         hbufu, attp, flags);
    k_attf<<<128, 256, 0, stream>>>(attp, fc_b, att, outF + 65536);
    k_scan3<<<128, 128, 0, stream>>>(xbf, i2h_w, h2h_w, i2h_b, h2h_b, att,
                                     h3u, hlast, flags + 4096);
    k_fc<<<256, 256, 0, stream>>>(hlast, fc0_w, fc0_b, out1);
    k_fc<<<256, 256, 0, stream>>>(out1, fc1_w, fc1_b, outF);
  }
}

// Round 21
// 7245.887 us; speedup vs baseline: 1.2283x; 1.2283x over previous
//
#include <hip/hip_runtime.h>
#include <cstdint>
#include <cstddef>

#define TDIM 512
#define BDIM 64
#define IDIM 512
#define HDIM 1024
#define SPIN_CAP 20000u
#define NREP 4  // fallback path only

typedef __attribute__((ext_vector_type(8))) short s16x8;
typedef __attribute__((ext_vector_type(4))) float f32x4;

__device__ __forceinline__ unsigned short f2bf(float f) {
  unsigned u = __builtin_bit_cast(unsigned, f);
  u += 0x7FFFu + ((u >> 16) & 1u);
  return (unsigned short)(u >> 16);
}
__device__ __forceinline__ float sigmf(float x) { return 1.0f / (1.0f + __expf(-x)); }
__device__ __forceinline__ unsigned pk2(float a, float b) {
  return (unsigned)f2bf(a) | ((unsigned)f2bf(b) << 16);
}
#define MFMA16(a, b, c) __builtin_amdgcn_mfma_f32_16x16x32_bf16((a), (b), (c), 0, 0, 0)

__device__ __forceinline__ s16x8 ld16_llc(const unsigned long long* p) {
  s16x8 v;
  asm volatile("global_load_dwordx4 %0, %1, off sc0 sc1" : "=v"(v) : "v"(p));
  return v;
}
__device__ __forceinline__ void sysst64(unsigned long long* p, unsigned long long v) {
  __hip_atomic_store(p, v, __ATOMIC_RELAXED, __HIP_MEMORY_SCOPE_SYSTEM);
}

// ---------------- x convert ----------------
__global__ __launch_bounds__(256) void k_xcvt(const float* __restrict__ x,
                                              unsigned short* __restrict__ xbf) {
  int idx = blockIdx.x * 256 + threadIdx.x;
  int i8 = idx * 8;
  int i = i8 & (IDIM - 1);
  int tb = i8 >> 9;
  int t = tb >> 6, b = tb & 63;
  const float* src = x + ((size_t)(b * TDIM + t)) * IDIM + i;
  float4 a = *(const float4*)src;
  float4 c = *(const float4*)(src + 4);
  uint4 v;
  v.x = pk2(a.x, a.y); v.y = pk2(a.z, a.w);
  v.z = pk2(c.x, c.y); v.w = pk2(c.z, c.w);
  *(uint4*)(xbf + i8) = v;
}

// ================= BIG PATH: write-once history + per-WAVE flags =================
// grid = 256 WGs x 128 thr (2 waves). dir = wg>>7, half = (wg>>6)&1, cg = wg&63.
// hist per chain: TDIM x 8192 u64. Producer WAVE publishes its own flag after its
// own vmcnt(0) ack (no __syncthreads on the critical path). 128 flags/chain,
// consumer lane l polls flags 2l and 2l+1 in one round trip.
__global__ __launch_bounds__(128, 1) void k_gru_big(
    const unsigned short* __restrict__ xbf,
    const float* __restrict__ wihf32f, const float* __restrict__ wihf32b,
    const float* __restrict__ whhf32f, const float* __restrict__ whhf32b,
    const float* __restrict__ bih_f, const float* __restrict__ bhh_f,
    const float* __restrict__ bih_b, const float* __restrict__ bhh_b,
    const float* __restrict__ attw,
    unsigned long long* __restrict__ ghist, float* __restrict__ attp,
    unsigned int* __restrict__ flags) {
  __shared__ uint4 lds4[147456 / 16];
  char* lds = (char*)lds4;
  const int wg = blockIdx.x;
  const int dir = wg >> 7, half = (wg >> 6) & 1, cg = wg & 63;
  const int tid = threadIdx.x, w = tid >> 6, l = tid & 63;
  const int r = l & 15, q = l >> 4;
  const int col = cg * 16 + r;
  const float* wih = dir ? wihf32b : wihf32f;
  const float* whh = dir ? whhf32b : whhf32f;
  const float* bih = dir ? bih_b : bih_f;
  const float* bhh = dir ? bhh_b : bhh_f;
  unsigned int* myflags = flags + (dir * 2 + half) * 2048;  // 128 flags x 64B
  unsigned long long* hist = ghist + (size_t)(dir * 2 + half) * ((size_t)TDIM * 8192);

  for (int it = tid; it < 48 * 128; it += 128) {
    int row = it >> 7, ch = it & 127;
    int g = row >> 4, rr = row & 15;
    const float* src = whh + ((size_t)(g * HDIM + cg * 16 + rr)) * HDIM + ch * 8;
    float4 f0 = *(const float4*)src;
    float4 f1 = *(const float4*)(src + 4);
    uint4 v;
    v.x = pk2(f0.x, f0.y); v.y = pk2(f0.z, f0.w);
    v.z = pk2(f1.x, f1.y); v.w = pk2(f1.z, f1.w);
    *(uint4*)(lds + row * 2048 + ((ch * 16) ^ ((row & 7) << 4))) = v;
  }
  for (int it = tid; it < 48 * 64; it += 128) {
    int row = it >> 6, ch = it & 63;
    int g = row >> 4, rr = row & 15;
    const float* src = wih + ((size_t)(g * HDIM + cg * 16 + rr)) * IDIM + ch * 8;
    float4 f0 = *(const float4*)src;
    float4 f1 = *(const float4*)(src + 4);
    uint4 v;
    v.x = pk2(f0.x, f0.y); v.y = pk2(f0.z, f0.w);
    v.z = pk2(f1.x, f1.y); v.w = pk2(f1.z, f1.w);
    *(uint4*)(lds + 98304 + row * 1024 + ((ch * 16) ^ ((row & 7) << 4))) = v;
  }
  __syncthreads();

  const float br = bih[col] + bhh[col];
  const float bz = bih[col + HDIM] + bhh[col + HDIM];
  const float bnx = bih[col + 2 * HDIM];
  const float bnh = bhh[col + 2 * HDIM];
  const float wfc = attw[dir * HDIM + col];
  const int swz = (r & 7) << 4;
  const int bb = half * 32 + w * 16;
  float h[4] = {0.f, 0.f, 0.f, 0.f};

  for (int t = 0; t < TDIM; ++t) {
    const int tt = dir ? (TDIM - 1 - t) : t;
    f32x4 aR = {}, aZ = {}, aNx = {}, aNh = {};
    // x-projection (no h dependency) before the wait
    {
      const unsigned short* px = xbf + ((size_t)(tt * BDIM + bb + r)) * IDIM + q * 8;
#pragma unroll 4
      for (int kt = 0; kt < 16; ++kt) {
        s16x8 a = *(const s16x8*)(px + kt * 32);
        int kb = q * 16 + kt * 64;
        s16x8 b0 = *(const s16x8*)(lds + 98304 + r * 1024 + (kb ^ swz));
        s16x8 b1 = *(const s16x8*)(lds + 98304 + (16 + r) * 1024 + (kb ^ swz));
        s16x8 b2 = *(const s16x8*)(lds + 98304 + (32 + r) * 1024 + (kb ^ swz));
        aR = MFMA16(a, b0, aR);
        aZ = MFMA16(a, b1, aZ);
        aNx = MFMA16(a, b2, aNx);
      }
    }
    if (t > 0) {
      // poll all 128 per-wave flags: lane l covers flags 2l, 2l+1
      for (unsigned spin = 0;; ++spin) {
        unsigned v0 = __hip_atomic_load(&myflags[(2 * l) * 16], __ATOMIC_RELAXED, __HIP_MEMORY_SCOPE_SYSTEM);
        unsigned v1 = __hip_atomic_load(&myflags[(2 * l + 1) * 16], __ATOMIC_RELAXED, __HIP_MEMORY_SCOPE_SYSTEM);
        unsigned v = v0 < v1 ? v0 : v1;
        if (__all((int)(v >= (unsigned)t))) break;
        if (spin > SPIN_CAP) break;  // watchdog
      }
      __builtin_amdgcn_sched_barrier(0);
      // h-projection from history[t-1]: plain cached loads (step-unique addresses)
      const unsigned long long* ph = hist + (size_t)(t - 1) * 8192 + (w * 16 + r) * 256 + q * 2;
      s16x8 ha[32];
#pragma unroll
      for (int i = 0; i < 32; ++i) ha[i] = *(const s16x8*)(ph + ((i + cg) & 31) * 8);
#pragma unroll
      for (int i = 0; i < 32; ++i) {
        int kro = (i + cg) & 31;
        int kb = q * 16 + kro * 64;
        s16x8 b0 = *(const s16x8*)(lds + r * 2048 + (kb ^ swz));
        s16x8 b1 = *(const s16x8*)(lds + (16 + r) * 2048 + (kb ^ swz));
        s16x8 b2 = *(const s16x8*)(lds + (32 + r) * 2048 + (kb ^ swz));
        aR = MFMA16(ha[i], b0, aR);
        aZ = MFMA16(ha[i], b1, aZ);
        aNh = MFMA16(ha[i], b2, aNh);
      }
    }
    unsigned long long* hn = hist + (size_t)t * 8192;
    float sa[4];
#pragma unroll
    for (int j = 0; j < 4; ++j) {
      const int lb = w * 16 + q * 4 + j;
      float rg = sigmf(aR[j] + br);
      float zg = sigmf(aZ[j] + bz);
      float ng = tanhf(aNx[j] + bnx + rg * (aNh[j] + bnh));
      float hv = (1.0f - zg) * ng + zg * h[j];
      h[j] = hv;
      sa[j] = hv * wfc;
      unsigned p2 = pk2(hv, __shfl_xor(hv, 1, 64));
      unsigned p2o = __shfl_xor(p2, 2, 64);
      if ((r & 3) == 0) {
        unsigned long long v64 = (unsigned long long)p2 | ((unsigned long long)p2o << 32);
        sysst64(&hn[(size_t)lb * 256 + cg * 4 + (r >> 2)], v64);
      }
    }
    // per-WAVE publish: this wave's 16 rows are entirely its own stores
    asm volatile("s_waitcnt vmcnt(0)" ::: "memory");
    if (l == 0)
      __hip_atomic_store(&myflags[(cg * 2 + w) * 16], (unsigned)(t + 1),
                         __ATOMIC_RELAXED, __HIP_MEMORY_SCOPE_SYSTEM);
    // attention partial: off the critical path
    {
      float* ap = attp + (size_t)(dir * 64 + cg) * (TDIM * BDIM) + tt * BDIM;
#pragma unroll
      for (int j = 0; j < 4; ++j) {
        const int b = half * 32 + w * 16 + q * 4 + j;
        float s = sa[j];
        s += __shfl_xor(s, 1, 64);
        s += __shfl_xor(s, 2, 64);
        s += __shfl_xor(s, 4, 64);
        s += __shfl_xor(s, 8, 64);
        if (r == 0) ap[b] = s;
      }
    }
  }
}

__global__ __launch_bounds__(128, 1) void k_scan3_big(
    const unsigned short* __restrict__ xbf,
    const float* __restrict__ i2hf32, const float* __restrict__ h2hf32,
    const float* __restrict__ i2hb, const float* __restrict__ h2hb,
    const float* __restrict__ att,
    unsigned long long* __restrict__ shist, float* __restrict__ hlast,
    unsigned int* __restrict__ flags3) {
  __shared__ uint4 lds4[49152 / 16];
  char* lds = (char*)lds4;
  const int wg = blockIdx.x;
  const int half = wg >> 6, cg = wg & 63;
  const int tid = threadIdx.x, w = tid >> 6, l = tid & 63;
  const int r = l & 15, q = l >> 4;
  const int col = cg * 16 + r;
  unsigned int* myflags = flags3 + half * 2048;
  unsigned long long* hist = shist + (size_t)half * ((size_t)TDIM * 8192);
  for (int it = tid; it < 16 * 128; it += 128) {
    int row = it >> 7, ch = it & 127;
    const float* src = h2hf32 + ((size_t)(cg * 16 + row)) * HDIM + ch * 8;
    float4 f0 = *(const float4*)src;
    float4 f1 = *(const float4*)(src + 4);
    uint4 v;
    v.x = pk2(f0.x, f0.y); v.y = pk2(f0.z, f0.w);
    v.z = pk2(f1.x, f1.y); v.w = pk2(f1.z, f1.w);
    *(uint4*)(lds + row * 2048 + ((ch * 16) ^ ((row & 7) << 4))) = v;
  }
  for (int it = tid; it < 16 * 64; it += 128) {
    int row = it >> 6, ch = it & 63;
    const float* src = i2hf32 + ((size_t)(cg * 16 + row)) * IDIM + ch * 8;
    float4 f0 = *(const float4*)src;
    float4 f1 = *(const float4*)(src + 4);
    uint4 v;
    v.x = pk2(f0.x, f0.y); v.y = pk2(f0.z, f0.w);
    v.z = pk2(f1.x, f1.y); v.w = pk2(f1.z, f1.w);
    *(uint4*)(lds + 32768 + row * 1024 + ((ch * 16) ^ ((row & 7) << 4))) = v;
  }
  __syncthreads();
  const float bc = i2hb[col] + h2hb[col];
  const int swz = (r & 7) << 4;
  const int bb = half * 32 + w * 16;
  float h[4] = {0.f, 0.f, 0.f, 0.f};
  for (int t = 0; t < TDIM; ++t) {
    f32x4 ac = {};
    {
      const unsigned short* px = xbf + ((size_t)(t * BDIM + bb + r)) * IDIM + q * 8;
#pragma unroll 4
      for (int kt = 0; kt < 16; ++kt) {
        s16x8 a = *(const s16x8*)(px + kt * 32);
        int kb = q * 16 + kt * 64;
        s16x8 b = *(const s16x8*)(lds + 32768 + r * 1024 + (kb ^ swz));
        ac = MFMA16(a, b, ac);
      }
    }
    if (t > 0) {
      for (unsigned spin = 0;; ++spin) {
        unsigned v0 = __hip_atomic_load(&myflags[(2 * l) * 16], __ATOMIC_RELAXED, __HIP_MEMORY_SCOPE_SYSTEM);
        unsigned v1 = __hip_atomic_load(&myflags[(2 * l + 1) * 16], __ATOMIC_RELAXED, __HIP_MEMORY_SCOPE_SYSTEM);
        unsigned v = v0 < v1 ? v0 : v1;
        if (__all((int)(v >= (unsigned)t))) break;
        if (spin > SPIN_CAP) break;  // watchdog
      }
      __builtin_amdgcn_sched_barrier(0);
      const unsigned long long* ph = hist + (size_t)(t - 1) * 8192 + (w * 16 + r) * 256 + q * 2;
      s16x8 ha[32];
#pragma unroll
      for (int i = 0; i < 32; ++i) ha[i] = *(const s16x8*)(ph + ((i + cg) & 31) * 8);
#pragma unroll
      for (int i = 0; i < 32; ++i) {
        int kro = (i + cg) & 31;
        int kb = q * 16 + kro * 64;
        s16x8 b = *(const s16x8*)(lds + r * 2048 + (kb ^ swz));
        ac = MFMA16(ha[i], b, ac);
      }
    }
    unsigned long long* hn = hist + (size_t)t * 8192;
    const float* ab = att + (size_t)t * BDIM;
#pragma unroll
    for (int j = 0; j < 4; ++j) {
      const int lb = w * 16 + q * 4 + j;
      float tr = fmaxf(ac[j] + bc, 0.0f);
      float a = ab[half * 32 + lb];
      float hv = a * tr + (1.0f - a) * h[j];
      h[j] = hv;
      unsigned p2 = pk2(hv, __shfl_xor(hv, 1, 64));
      unsigned p2o = __shfl_xor(p2, 2, 64);
      if ((r & 3) == 0) {
        unsigned long long v64 = (unsigned long long)p2 | ((unsigned long long)p2o << 32);
        sysst64(&hn[(size_t)lb * 256 + cg * 4 + (r >> 2)], v64);
      }
    }
    asm volatile("s_waitcnt vmcnt(0)" ::: "memory");
    if (l == 0)
      __hip_atomic_store(&myflags[(cg * 2 + w) * 16], (unsigned)(t + 1),
                         __ATOMIC_RELAXED, __HIP_MEMORY_SCOPE_SYSTEM);
  }
#pragma unroll
  for (int j = 0; j < 4; ++j) {
    const int b = half * 32 + w * 16 + q * 4 + j;
    hlast[b * HDIM + col] = h[j];
  }
}

// ================= FALLBACK PATH (round-18, passing at 8.0 ms) =================
__global__ __launch_bounds__(128, 1) void k_gru_fused(
    const unsigned short* __restrict__ xbf,
    const float* __restrict__ wihf32f, const float* __restrict__ wihf32b,
    const float* __restrict__ whhf32f, const float* __restrict__ whhf32b,
    const float* __restrict__ bih_f, const float* __restrict__ bhh_f,
    const float* __restrict__ bih_b, const float* __restrict__ bhh_b,
    const float* __restrict__ attw,
    unsigned long long* __restrict__ hbufu, float* __restrict__ attp,
    unsigned int* __restrict__ flags) {
  __shared__ uint4 lds4[147456 / 16];
  char* lds = (char*)lds4;
  const int wg = blockIdx.x;
  const int dir = wg >> 7, half = (wg >> 6) & 1, cg = wg & 63;
  const int tid = threadIdx.x, w = tid >> 6, l = tid & 63;
  const int r = l & 15, q = l >> 4;
  const int col = cg * 16 + r;
  const float* wih = dir ? wihf32b : wihf32f;
  const float* whh = dir ? whhf32b : whhf32f;
  const float* bih = dir ? bih_b : bih_f;
  const float* bhh = dir ? bhh_b : bhh_f;
  unsigned int* myflags = flags + (dir * 2 + half) * 1024;
  unsigned long long* hb0 = hbufu + (size_t)(dir * 2 + half) * (NREP * 2 * 8192);

  for (int it = tid; it < 48 * 128; it += 128) {
    int row = it >> 7, ch = it & 127;
    int g = row >> 4, rr = row & 15;
    const float* src = whh + ((size_t)(g * HDIM + cg * 16 + rr)) * HDIM + ch * 8;
    float4 f0 = *(const float4*)src;
    float4 f1 = *(const float4*)(src + 4);
    uint4 v;
    v.x = pk2(f0.x, f0.y); v.y = pk2(f0.z, f0.w);
    v.z = pk2(f1.x, f1.y); v.w = pk2(f1.z, f1.w);
    *(uint4*)(lds + row * 2048 + ((ch * 16) ^ ((row & 7) << 4))) = v;
  }
  for (int it = tid; it < 48 * 64; it += 128) {
    int row = it >> 6, ch = it & 63;
    int g = row >> 4, rr = row & 15;
    const float* src = wih + ((size_t)(g * HDIM + cg * 16 + rr)) * IDIM + ch * 8;
    float4 f0 = *(const float4*)src;
    float4 f1 = *(const float4*)(src + 4);
    uint4 v;
    v.x = pk2(f0.x, f0.y); v.y = pk2(f0.z, f0.w);
    v.z = pk2(f1.x, f1.y); v.w = pk2(f1.z, f1.w);
    *(uint4*)(lds + 98304 + row * 1024 + ((ch * 16) ^ ((row & 7) << 4))) = v;
  }
  __syncthreads();

  const float br = bih[col] + bhh[col];
  const float bz = bih[col + HDIM] + bhh[col + HDIM];
  const float bnx = bih[col + 2 * HDIM];
  const float bnh = bhh[col + 2 * HDIM];
  const float wfc = attw[dir * HDIM + col];
  const int swz = (r & 7) << 4;
  const int bb = half * 32 + w * 16;
  float h[4] = {0.f, 0.f, 0.f, 0.f};

  for (int t = 0; t < TDIM; ++t) {
    const int tt = dir ? (TDIM - 1 - t) : t;
    f32x4 aR = {}, aZ = {}, aNx = {}, aNh = {};
    {
      const unsigned short* px = xbf + ((size_t)(tt * BDIM + bb + r)) * IDIM + q * 8;
#pragma unroll 4
      for (int kt = 0; kt < 16; ++kt) {
        s16x8 a = *(const s16x8*)(px + kt * 32);
        int kb = q * 16 + kt * 64;
        s16x8 b0 = *(const s16x8*)(lds + 98304 + r * 1024 + (kb ^ swz));
        s16x8 b1 = *(const s16x8*)(lds + 98304 + (16 + r) * 1024 + (kb ^ swz));
        s16x8 b2 = *(const s16x8*)(lds + 98304 + (32 + r) * 1024 + (kb ^ swz));
        aR = MFMA16(a, b0, aR);
        aZ = MFMA16(a, b1, aZ);
        aNx = MFMA16(a, b2, aNx);
      }
    }
    if (t > 0) {
      for (unsigned spin = 0;; ++spin) {
        unsigned v = __hip_atomic_load(&myflags[l * 16], __ATOMIC_RELAXED, __HIP_MEMORY_SCOPE_SYSTEM);
        if (__all((int)(v >= (unsigned)t))) break;
        if (spin > SPIN_CAP) break;
      }
      __builtin_amdgcn_sched_barrier(0);
    }
    {
      const unsigned long long* ph = hb0 + (size_t)(cg & (NREP - 1)) * 16384 +
                                     (size_t)(t & 1) * 8192 + (w * 16 + r) * 256 + q * 2;
      s16x8 ha[32];
#pragma unroll
      for (int i = 0; i < 32; ++i) {
        int kro = (i + cg) & 31;
        ha[i] = ld16_llc(ph + kro * 8);
      }
      asm volatile("s_waitcnt vmcnt(0)" ::: "memory");
      __builtin_amdgcn_sched_barrier(0);
#pragma unroll
      for (int i = 0; i < 32; ++i) {
        int kro = (i + cg) & 31;
        int kb = q * 16 + kro * 64;
        s16x8 b0 = *(const s16x8*)(lds + r * 2048 + (kb ^ swz));
        s16x8 b1 = *(const s16x8*)(lds + (16 + r) * 2048 + (kb ^ swz));
        s16x8 b2 = *(const s16x8*)(lds + (32 + r) * 2048 + (kb ^ swz));
        aR = MFMA16(ha[i], b0, aR);
        aZ = MFMA16(ha[i], b1, aZ);
        aNh = MFMA16(ha[i], b2, aNh);
      }
    }
    unsigned long long* hn = hb0 + (size_t)((t + 1) & 1) * 8192;
    float sa[4];
#pragma unroll
    for (int j = 0; j < 4; ++j) {
      const int lb = w * 16 + q * 4 + j;
      float rg = sigmf(aR[j] + br);
      float zg = sigmf(aZ[j] + bz);
      float ng = tanhf(aNx[j] + bnx + rg * (aNh[j] + bnh));
      float hv = (1.0f - zg) * ng + zg * h[j];
      h[j] = hv;
      sa[j] = hv * wfc;
      unsigned p2 = pk2(hv, __shfl_xor(hv, 1, 64));
      unsigned p2o = __shfl_xor(p2, 2, 64);
      if ((r & 3) == 0) {
        unsigned long long v64 = (unsigned long long)p2 | ((unsigned long long)p2o << 32);
        size_t off = (size_t)lb * 256 + cg * 4 + (r >> 2);
#pragma unroll
        for (int rep = 0; rep < NREP; ++rep)
          sysst64(&hn[(size_t)rep * 16384 + off], v64);
      }
    }
    asm volatile("s_waitcnt vmcnt(0)" ::: "memory");
    __syncthreads();
    if (tid == 0)
      __hip_atomic_store(&myflags[cg * 16], (unsigned)(t + 1),
                         __ATOMIC_RELAXED, __HIP_MEMORY_SCOPE_SYSTEM);
    {
      float* ap = attp + (size_t)(dir * 64 + cg) * (TDIM * BDIM) + tt * BDIM;
#pragma unroll
      for (int j = 0; j < 4; ++j) {
        const int b = half * 32 + w * 16 + q * 4 + j;
        float s = sa[j];
        s += __shfl_xor(s, 1, 64);
        s += __shfl_xor(s, 2, 64);
        s += __shfl_xor(s, 4, 64);
        s += __shfl_xor(s, 8, 64);
        if (r == 0) ap[b] = s;
      }
    }
  }
}

__global__ __launch_bounds__(128, 1) void k_scan3(
    const unsigned short* __restrict__ xbf,
    const float* __restrict__ i2hf32, const float* __restrict__ h2hf32,
    const float* __restrict__ i2hb, const float* __restrict__ h2hb,
    const float* __restrict__ att,
    unsigned long long* __restrict__ h3u, float* __restrict__ hlast,
    unsigned int* __restrict__ flags3) {
  __shared__ uint4 lds4[49152 / 16];
  char* lds = (char*)lds4;
  const int wg = blockIdx.x;
  const int half = wg >> 6, cg = wg & 63;
  const int tid = threadIdx.x, w = tid >> 6, l = tid & 63;
  const int r = l & 15, q = l >> 4;
  const int col = cg * 16 + r;
  unsigned int* myflags = flags3 + half * 1024;
  unsigned long long* hb0 = h3u + (size_t)half * (NREP * 2 * 8192);
  for (int it = tid; it < 16 * 128; it += 128) {
    int row = it >> 7, ch = it & 127;
    const float* src = h2hf32 + ((size_t)(cg * 16 + row)) * HDIM + ch * 8;
    float4 f0 = *(const float4*)src;
    float4 f1 = *(const float4*)(src + 4);
    uint4 v;
    v.x = pk2(f0.x, f0.y); v.y = pk2(f0.z, f0.w);
    v.z = pk2(f1.x, f1.y); v.w = pk2(f1.z, f1.w);
    *(uint4*)(lds + row * 2048 + ((ch * 16) ^ ((row & 7) << 4))) = v;
  }
  for (int it = tid; it < 16 * 64; it += 128) {
    int row = it >> 6, ch = it & 63;
    const float* src = i2hf32 + ((size_t)(cg * 16 + row)) * IDIM + ch * 8;
    float4 f0 = *(const float4*)src;
    float4 f1 = *(const float4*)(src + 4);
    uint4 v;
    v.x = pk2(f0.x, f0.y); v.y = pk2(f0.z, f0.w);
    v.z = pk2(f1.x, f1.y); v.w = pk2(f1.z, f1.w);
    *(uint4*)(lds + 32768 + row * 1024 + ((ch * 16) ^ ((row & 7) << 4))) = v;
  }
  __syncthreads();
  const float bc = i2hb[col] + h2hb[col];
  const int swz = (r & 7) << 4;
  const int bb = half * 32 + w * 16;
  float h[4] = {0.f, 0.f, 0.f, 0.f};
  for (int t = 0; t < TDIM; ++t) {
    f32x4 ac = {};
    {
      const unsigned short* px = xbf + ((size_t)(t * BDIM + bb + r)) * IDIM + q * 8;
#pragma unroll 4
      for (int kt = 0; kt < 16; ++kt) {
        s16x8 a = *(const s16x8*)(px + kt * 32);
        int kb = q * 16 + kt * 64;
        s16x8 b = *(const s16x8*)(lds + 32768 + r * 1024 + (kb ^ swz));
        ac = MFMA16(a, b, ac);
      }
    }
    if (t > 0) {
      for (unsigned spin = 0;; ++spin) {
        unsigned v = __hip_atomic_load(&myflags[l * 16], __ATOMIC_RELAXED, __HIP_MEMORY_SCOPE_SYSTEM);
        if (__all((int)(v >= (unsigned)t))) break;
        if (spin > SPIN_CAP) break;
      }
      __builtin_amdgcn_sched_barrier(0);
    }
    {
      const unsigned long long* ph = hb0 + (size_t)(cg & (NREP - 1)) * 16384 +
                                     (size_t)(t & 1) * 8192 + (w * 16 + r) * 256 + q * 2;
      s16x8 ha[32];
#pragma unroll
      for (int i = 0; i < 32; ++i) {
        int kro = (i + cg) & 31;
        ha[i] = ld16_llc(ph + kro * 8);
      }
      asm volatile("s_waitcnt vmcnt(0)" ::: "memory");
      __builtin_amdgcn_sched_barrier(0);
#pragma unroll
      for (int i = 0; i < 32; ++i) {
        int kro = (i + cg) & 31;
        int kb = q * 16 + kro * 64;
        s16x8 b = *(const s16x8*)(lds + r * 2048 + (kb ^ swz));
        ac = MFMA16(ha[i], b, ac);
      }
    }
    unsigned long long* hn = hb0 + (size_t)((t + 1) & 1) * 8192;
    const float* ab = att + (size_t)t * BDIM;
#pragma unroll
    for (int j = 0; j < 4; ++j) {
      const int lb = w * 16 + q * 4 + j;
      float tr = fmaxf(ac[j] + bc, 0.0f);
      float a = ab[half * 32 + lb];
      float hv = a * tr + (1.0f - a) * h[j];
      h[j] = hv;
      unsigned p2 = pk2(hv, __shfl_xor(hv, 1, 64));
      unsigned p2o = __shfl_xor(p2, 2, 64);
      if ((r & 3) == 0) {
        unsigned long long v64 = (unsigned long long)p2 | ((unsigned long long)p2o << 32);
        size_t off = (size_t)lb * 256 + cg * 4 + (r >> 2);
#pragma unroll
        for (int rep = 0; rep < NREP; ++rep)
          sysst64(&hn[(size_t)rep * 16384 + off], v64);
      }
    }
    asm volatile("s_waitcnt vmcnt(0)" ::: "memory");
    __syncthreads();
    if (tid == 0)
      __hip_atomic_store(&myflags[cg * 16], (unsigned)(t + 1),
                         __ATOMIC_RELAXED, __HIP_MEMORY_SCOPE_SYSTEM);
  }
#pragma unroll
  for (int j = 0; j < 4; ++j) {
    const int b = half * 32 + w * 16 + q * 4 + j;
    hlast[b * HDIM + col] = h[j];
  }
}

// ---------------- shared epilogue kernels ----------------
__global__ __launch_bounds__(256) void k_attf(const float* __restrict__ attp,
                                              const float* __restrict__ fcb,
                                              float* __restrict__ att,
                                              float* __restrict__ att_out) {
  int idx = blockIdx.x * 256 + threadIdx.x;
  float s = fcb[0];
  for (int g = 0; g < 128; ++g) s += attp[(size_t)g * (TDIM * BDIM) + idx];
  float a = sigmf(3.0f * s);
  att[idx] = a;
  int t = idx >> 6, b = idx & 63;
  att_out[(size_t)b * TDIM + t] = a;
}

__global__ __launch_bounds__(256) void k_fc(const float* __restrict__ A,
                                            const float* __restrict__ W,
                                            const float* __restrict__ bias,
                                            float* __restrict__ dst) {
  const int idx = blockIdx.x * 256 + threadIdx.x;
  const int rr = idx >> 10, c = idx & 1023;
  const float4* a = (const float4*)(A + (size_t)rr * HDIM);
  const float4* w = (const float4*)(W + (size_t)c * HDIM);
  float s = bias[c];
  for (int k = 0; k < HDIM / 4; ++k) {
    float4 xx = a[k], y = w[k];
    s += xx.x * y.x + xx.y * y.y + xx.z * y.z + xx.w * y.w;
  }
  dst[idx] = s;
}

__global__ __launch_bounds__(256) void k_diag(float* out, int n, float val) {
  int i = blockIdx.x * 256 + threadIdx.x;
  if (i < n) out[i] = val;
}

extern "C" void kernel_launch(void* const* d_in, const int* in_sizes, int n_in,
                              void* d_out, int out_size, void* d_ws, size_t ws_size,
                              hipStream_t stream) {
  float* outF = (float*)d_out;
  int diag_blocks = (out_size + 255) / 256;

  static const int exp_sizes[19] = {16777216, 1572864, 3145728, 3072, 3072,
                                    1572864, 3145728, 3072, 3072, 2048, 1,
                                    524288, 1024, 1048576, 1024, 1048576, 1024,
                                    1048576, 1024};
  if (n_in != 19) {
    k_diag<<<diag_blocks, 256, 0, stream>>>(outF, out_size, 3999.0f);
    return;
  }
  for (int i = 0; i < 19; ++i) {
    if (in_sizes[i] != exp_sizes[i]) {
      k_diag<<<diag_blocks, 256, 0, stream>>>(outF, out_size, (float)(4000 + i * 16));
      return;
    }
  }

  const float* x     = (const float*)d_in[0];
  const float* wih_f = (const float*)d_in[1];
  const float* whh_f = (const float*)d_in[2];
  const float* bih_f = (const float*)d_in[3];
  const float* bhh_f = (const float*)d_in[4];
  const float* wih_b = (const float*)d_in[5];
  const float* whh_b = (const float*)d_in[6];
  const float* bih_b = (const float*)d_in[7];
  const float* bhh_b = (const float*)d_in[8];
  const float* fc_w  = (const float*)d_in[9];
  const float* fc_b  = (const float*)d_in[10];
  const float* i2h_w = (const float*)d_in[11];
  const float* i2h_b = (const float*)d_in[12];
  const float* h2h_w = (const float*)d_in[13];
  const float* h2h_b = (const float*)d_in[14];
  const float* fc0_w = (const float*)d_in[15];
  const float* fc0_b = (const float*)d_in[16];
  const float* fc1_w = (const float*)d_in[17];
  const float* fc1_b = (const float*)d_in[18];

  const size_t OFF_XBF  = 0;           // 33,554,432
  const size_t OFF_ATTP = 33554432;    // 16,777,216
  const size_t OFF_ATT  = 50331648;    //    131,072

  // BIG layout (write-once histories + per-wave flags)
  const size_t OFF_GHIST = 50462720;                 // 134,217,728
  const size_t OFF_SHIST = OFF_GHIST + 134217728;    //  67,108,864
  const size_t OFF_HLAST_B = OFF_SHIST + 67108864;   //     262,144
  const size_t OFF_OUT1_B  = OFF_HLAST_B + 262144;   //     262,144
  const size_t OFF_FLAGS_B = OFF_OUT1_B + 262144;    //      49,152 (6 chains x 128 flags x 64B)
  const size_t TOTAL_BIG   = OFF_FLAGS_B + 49152;

  // FALLBACK layout (round-18)
  const size_t OFF_HBUF  = 50462720;
  const size_t OFF_H3BUF = 52559872;
  const size_t OFF_HLAST = 53608448;
  const size_t OFF_OUT1  = 53870592;
  const size_t OFF_FLAGS = 54132736;
  const size_t TOTAL_SMALL = 54157312;

  if (ws_size < TOTAL_SMALL) {
    k_diag<<<diag_blocks, 256, 0, stream>>>(outF, out_size, (float)(ws_size >> 20));
    return;
  }

  char* ws = (char*)d_ws;
  unsigned short* xbf = (unsigned short*)(ws + OFF_XBF);
  float* attp         = (float*)(ws + OFF_ATTP);
  float* att          = (float*)(ws + OFF_ATT);

  k_xcvt<<<8192, 256, 0, stream>>>(x, xbf);

  if (ws_size >= TOTAL_BIG) {
    // ---------- BIG PATH: per-wave flags, barrier-free publish ----------
    unsigned long long* ghist = (unsigned long long*)(ws + OFF_GHIST);
    unsigned long long* shist = (unsigned long long*)(ws + OFF_SHIST);
    float* hlast              = (float*)(ws + OFF_HLAST_B);
    float* out1               = (float*)(ws + OFF_OUT1_B);
    unsigned int* flags       = (unsigned int*)(ws + OFF_FLAGS_B);

    hipMemsetAsync(flags, 0, 49152, stream);

    k_gru_big<<<256, 128, 0, stream>>>(xbf, wih_f, wih_b, whh_f, whh_b,
                                       bih_f, bhh_f, bih_b, bhh_b, fc_w,
                                       ghist, attp, flags);
    k_attf<<<128, 256, 0, stream>>>(attp, fc_b, att, outF + 65536);
    k_scan3_big<<<128, 128, 0, stream>>>(xbf, i2h_w, h2h_w, i2h_b, h2h_b, att,
                                         shist, hlast, flags + 8192);
    k_fc<<<256, 256, 0, stream>>>(hlast, fc0_w, fc0_b, out1);
    k_fc<<<256, 256, 0, stream>>>(out1, fc1_w, fc1_b, outF);
  } else {
    // ---------- FALLBACK (round-18) ----------
    unsigned long long* hbufu = (unsigned long long*)(ws + OFF_HBUF);
    unsigned long long* h3u   = (unsigned long long*)(ws + OFF_H3BUF);
    float* hlast              = (float*)(ws + OFF_HLAST);
    float* out1               = (float*)(ws + OFF_OUT1);
    unsigned int* flags       = (unsigned int*)(ws + OFF_FLAGS);

    hipMemsetAsync(flags, 0, 24576, stream);
    hipMemsetAsync(hbufu, 0, 2097152, stream);
    hipMemsetAsync(h3u, 0, 1048576, stream);

    k_gru_fused<<<256, 128, 0, stream>>>(xbf, wih_f, wih_b, whh_f, whh_b,
                                         bih_f, bhh_f, bih_b, bhh_b, fc_w,
                                         hbufu, attp, flags);
    k_attf<<<128, 256, 0, stream>>>(attp, fc_b, att, outF + 65536);
    k_scan3<<<128, 128, 0, stream>>>(xbf, i2h_w, h2h_w, i2h_b, h2h_b, att,
                                     h3u, hlast, flags + 4096);
    k_fc<<<256, 256, 0, stream>>>(hlast, fc0_w, fc0_b, out1);
    k_fc<<<256, 256, 0, stream>>>(out1, fc1_w, fc1_b, outF);
  }
}